// Round 1
// baseline (10678.591 us; speedup 1.0000x reference)
//
#include <hip/hip_runtime.h>
#include <hip/hip_fp16.h>

#define DD 1024
#define TSTEPS 1024
#define BATCH 8
#define NWG 64
#define ROWS 16
#define HFS 1028   // LDS hf row stride in halves (514 dwords, 514%32=2 -> conflict-free-ish)

typedef _Float16 half8 __attribute__((ext_vector_type(8)));
typedef float floatx4 __attribute__((ext_vector_type(4)));

// ---- d_out float offsets ----
#define OUT_OFF   0
#define LOGH_OFF  8388608
#define SIGNH_OFF 16785408
#define HLIN_OFF  25182208

// ---- ws byte offsets ----
#define WS_SCALES  0          // float[2]
#define WS_SUMSQ   64         // float[2][8]
#define WS_CNTS    384        // int[2][8] spectral barriers -> [384,448)
#define WS_SPECVEC 512        // float[2][2][1024] power-iter ping-pong -> [512,16896)
#define WS_COMM    16896      // unsigned[2][8][1024] tagged payload dwords -> [16896,82432)
// Each comm dword: (step_tag << 16) | f16(h). Tag t+1 is written at step t.
// Tags are unique per step (1..1024), so data+readiness land atomically in one
// dword store: no flags, no producer vmcnt, no store ordering needed.
// NOTE: comm MUST be zeroed every launch (stale tags from a previous replay
// would alias with this run's tags) -> memset covers [0, WS_COMM + 65536).

__device__ __forceinline__ int aload_i(int* p) { return __hip_atomic_load(p, __ATOMIC_RELAXED, __HIP_MEMORY_SCOPE_AGENT); }
__device__ __forceinline__ float aload_f(float* p) { return __hip_atomic_load(p, __ATOMIC_RELAXED, __HIP_MEMORY_SCOPE_AGENT); }
__device__ __forceinline__ unsigned aload_u(unsigned* p) { return __hip_atomic_load(p, __ATOMIC_RELAXED, __HIP_MEMORY_SCOPE_AGENT); }
__device__ __forceinline__ void astore_f(float* p, float v) { __hip_atomic_store(p, v, __ATOMIC_RELAXED, __HIP_MEMORY_SCOPE_AGENT); }
__device__ __forceinline__ void astore_i(int* p, int v) { __hip_atomic_store(p, v, __ATOMIC_RELAXED, __HIP_MEMORY_SCOPE_AGENT); }
__device__ __forceinline__ void astore_u(unsigned* p, unsigned v) { __hip_atomic_store(p, v, __ATOMIC_RELAXED, __HIP_MEMORY_SCOPE_AGENT); }
__device__ __forceinline__ void aadd_i(int* p, int v) { (void)__hip_atomic_fetch_add(p, v, __ATOMIC_RELAXED, __HIP_MEMORY_SCOPE_AGENT); }
__device__ __forceinline__ void waitcnt_vm0() { asm volatile("s_waitcnt vmcnt(0)" ::: "memory"); }

// ============================================================================
// Spectral norm: 3-step power iteration for both matrices concurrently.
// ============================================================================
__global__ __launch_bounds__(256) void spectral_kernel(
    const float* __restrict__ Wh, const float* __restrict__ Wd,
    const float* __restrict__ uh, const float* __restrict__ ud,
    unsigned char* __restrict__ ws) {
  const int g  = blockIdx.x >> 6;
  const int wg = blockIdx.x & 63;
  const int tid = threadIdx.x;
  const float* W  = g ? Wd : Wh;
  const float* u0 = g ? ud : uh;
  float* scales = (float*)(ws + WS_SCALES);
  float* sumsq  = (float*)(ws + WS_SUMSQ) + g*8;
  int*   cnt    = (int*)(ws + WS_CNTS) + g*8;
  float* ubuf   = (float*)(ws + WS_SPECVEC) + g*2048;
  float* vbuf   = ubuf + 1024;

  __shared__ float xs[1024];
  __shared__ float tileW[256*17];
  __shared__ float red[16*17];

  float ss = 0.f;
  for (int i2 = tid; i2 < 1024; i2 += 256) { float x = u0[i2]; ss += x*x; }
  #pragma unroll
  for (int off = 1; off < 64; off <<= 1) ss += __shfl_xor(ss, off);
  if ((tid & 63) == 0) red[tid >> 6] = ss;
  __syncthreads();
  float inv_prev = 1.f/(sqrtf(red[0]+red[1]+red[2]+red[3]) + 1e-8f);
  __syncthreads();

  for (int p = 1; p <= 6; ++p) {
    const int colmv = p & 1;
    float* dst  = colmv ? vbuf : ubuf;
    float* srcw = colmv ? ubuf : vbuf;
    float part = 0.f;
    if (colmv) {
      const int jb = wg*16;
      const int jl = tid & 15, is = tid >> 4;
      float acc = 0.f;
      for (int i0 = 0; i0 < 1024; i0 += 256) {
        __syncthreads();
        float xv = (p == 1) ? u0[i0 + tid] : aload_f(srcw + i0 + tid);
        xs[tid] = xv * inv_prev;
        const float* wr = W + (size_t)(i0 + tid)*DD + jb;
        float4 a = *(const float4*)(wr + 0);
        float4 bq = *(const float4*)(wr + 4);
        float4 cq = *(const float4*)(wr + 8);
        float4 dq = *(const float4*)(wr + 12);
        float* tr = tileW + tid*17;
        tr[0]=a.x; tr[1]=a.y; tr[2]=a.z; tr[3]=a.w;
        tr[4]=bq.x; tr[5]=bq.y; tr[6]=bq.z; tr[7]=bq.w;
        tr[8]=cq.x; tr[9]=cq.y; tr[10]=cq.z; tr[11]=cq.w;
        tr[12]=dq.x; tr[13]=dq.y; tr[14]=dq.z; tr[15]=dq.w;
        __syncthreads();
        #pragma unroll 4
        for (int ii = 0; ii < 16; ++ii)
          acc += tileW[(is*16 + ii)*17 + jl] * xs[is*16 + ii];
      }
      __syncthreads();
      red[is*17 + jl] = acc;
      __syncthreads();
      if (tid < 16) {
        float y = 0.f;
        #pragma unroll
        for (int k = 0; k < 16; ++k) y += red[k*17 + tid];
        astore_f(dst + jb + tid, y);
        part = y*y;
      }
    } else {
      const int ib = wg*16;
      for (int i2 = tid; i2 < 1024; i2 += 256) xs[i2] = aload_f(srcw + i2) * inv_prev;
      __syncthreads();
      const int r = tid >> 4, s = tid & 15;
      const float* wr = W + (size_t)(ib + r)*DD;
      float acc = 0.f;
      #pragma unroll 8
      for (int jj = 0; jj < 64; ++jj) {
        int j = s + (jj << 4);
        acc += wr[j] * xs[j];
      }
      #pragma unroll
      for (int off = 1; off < 16; off <<= 1) acc += __shfl_xor(acc, off);
      __syncthreads();
      if (s == 0) red[r] = acc;
      __syncthreads();
      if (tid < 16) {
        float y = red[tid];
        astore_f(dst + ib + tid, y);
        part = y*y;
      }
    }
    #pragma unroll
    for (int off = 1; off < 16; off <<= 1) part += __shfl_xor(part, off);
    if (tid == 0) atomicAdd(sumsq + p, part);
    waitcnt_vm0();
    __syncthreads();
    if (tid == 0) {
      aadd_i(cnt + p, 1);
      while (aload_i(cnt + p) < 64) __builtin_amdgcn_s_sleep(1);
    }
    __syncthreads();
    float stot = aload_f(sumsq + p);
    inv_prev = 1.f/(sqrtf(stot) + 1e-8f);
    __syncthreads();
  }
  if (wg == 0 && tid == 0) {
    float n2 = aload_f(sumsq + 6);
    float nn = sqrtf(n2);
    float sigma = (nn*nn)/(nn + 1e-8f);
    scales[g] = 0.99f/(sigma + 1e-8f);
  }
}

// ============================================================================
// f16 MFMA GEMM (dual-B variant shares the A tile). M=8192, N=K=1024.
// ============================================================================
__device__ __forceinline__ half8 cvt8(const float* p) {
  float4 lo = *(const float4*)p;
  float4 hi = *(const float4*)(p+4);
  half8 h;
  h[0]=(_Float16)lo.x; h[1]=(_Float16)lo.y; h[2]=(_Float16)lo.z; h[3]=(_Float16)lo.w;
  h[4]=(_Float16)hi.x; h[5]=(_Float16)hi.y; h[6]=(_Float16)hi.z; h[7]=(_Float16)hi.w;
  return h;
}

__global__ __launch_bounds__(256) void gemm_f16(
    const float* __restrict__ A,
    const float* __restrict__ B1, const float* __restrict__ B2,
    const float* __restrict__ bias1, const float* __restrict__ bias2,
    float* __restrict__ C1, float* __restrict__ C2) {
  const int n0 = blockIdx.x * 64;
  const int m0 = blockIdx.y * 64;
  const int tid = threadIdx.x;
  const int wave = tid >> 6, lane = tid & 63;
  const int quad = lane >> 4, l16 = lane & 15;
  const bool dual = (B2 != nullptr);
  __shared__ _Float16 As[64*40];
  __shared__ _Float16 Bs1[64*40];
  __shared__ _Float16 Bs2[64*40];
  floatx4 zero = {0.f,0.f,0.f,0.f};
  floatx4 acc1[2][2] = {{zero,zero},{zero,zero}};
  floatx4 acc2[2][2] = {{zero,zero},{zero,zero}};
  const int srow = tid >> 2;
  const int sseg = (tid & 3) * 8;
  const int mb = (wave >> 1)*32, nb = (wave & 1)*32;
  for (int k0 = 0; k0 < 1024; k0 += 32) {
    __syncthreads();
    *(half8*)&As[srow*40 + sseg]  = cvt8(A  + (size_t)(m0+srow)*DD + k0 + sseg);
    *(half8*)&Bs1[srow*40 + sseg] = cvt8(B1 + (size_t)(n0+srow)*DD + k0 + sseg);
    if (dual) *(half8*)&Bs2[srow*40 + sseg] = cvt8(B2 + (size_t)(n0+srow)*DD + k0 + sseg);
    __syncthreads();
    half8 a0 = *(const half8*)&As[(mb + l16)*40 + quad*8];
    half8 a1 = *(const half8*)&As[(mb + 16 + l16)*40 + quad*8];
    half8 b0 = *(const half8*)&Bs1[(nb + l16)*40 + quad*8];
    half8 b1 = *(const half8*)&Bs1[(nb + 16 + l16)*40 + quad*8];
    acc1[0][0] = __builtin_amdgcn_mfma_f32_16x16x32_f16(a0, b0, acc1[0][0], 0,0,0);
    acc1[0][1] = __builtin_amdgcn_mfma_f32_16x16x32_f16(a0, b1, acc1[0][1], 0,0,0);
    acc1[1][0] = __builtin_amdgcn_mfma_f32_16x16x32_f16(a1, b0, acc1[1][0], 0,0,0);
    acc1[1][1] = __builtin_amdgcn_mfma_f32_16x16x32_f16(a1, b1, acc1[1][1], 0,0,0);
    if (dual) {
      half8 c0 = *(const half8*)&Bs2[(nb + l16)*40 + quad*8];
      half8 c1 = *(const half8*)&Bs2[(nb + 16 + l16)*40 + quad*8];
      acc2[0][0] = __builtin_amdgcn_mfma_f32_16x16x32_f16(a0, c0, acc2[0][0], 0,0,0);
      acc2[0][1] = __builtin_amdgcn_mfma_f32_16x16x32_f16(a0, c1, acc2[0][1], 0,0,0);
      acc2[1][0] = __builtin_amdgcn_mfma_f32_16x16x32_f16(a1, c0, acc2[1][0], 0,0,0);
      acc2[1][1] = __builtin_amdgcn_mfma_f32_16x16x32_f16(a1, c1, acc2[1][1], 0,0,0);
    }
  }
  #pragma unroll
  for (int in = 0; in < 2; ++in) {
    const int n = n0 + nb + in*16 + l16;
    const float bv1 = bias1 ? bias1[n] : 0.f;
    const float bv2 = (dual && bias2) ? bias2[n] : 0.f;
    #pragma unroll
    for (int im = 0; im < 2; ++im) {
      const int mrow = m0 + mb + im*16 + quad*4;
      floatx4 c = acc1[im][in];
      #pragma unroll
      for (int r2 = 0; r2 < 4; ++r2) C1[(size_t)(mrow + r2)*DD + n] = c[r2] + bv1;
      if (dual) {
        floatx4 c2 = acc2[im][in];
        #pragma unroll
        for (int r2 = 0; r2 < 4; ++r2) C2[(size_t)(mrow + r2)*DD + n] = c2[r2] + bv2;
      }
    }
  }
}

// ============================================================================
// Persistent recurrence, tagged-payload synced:
// 64 WGs x 256 thr; WG owns 16 rows; weights register-resident as MFMA A-frags.
// Exchange dword = (tag<<16)|f16(h): data + readiness land in ONE atomic dword
// store. Producer fire-and-forgets 128 dword stores (no vmcnt, no flag).
// Consumer spins on the payload itself: unrolled predicated 32-load sweeps,
// re-reading only still-pending dwords after the first sweep. Exact-tag match
// (tags unique per step) preserves the all-barrier + double-buffer safety.
// ============================================================================
__global__ __launch_bounds__(256, 1) void recurrence_kernel(
    const float* __restrict__ Rh_raw, const float* __restrict__ Rd_raw,
    const float* __restrict__ logh0, const float* __restrict__ signh0,
    float* __restrict__ dout, unsigned char* __restrict__ ws) {
  const int wg = blockIdx.x;
  const int i0 = wg * ROWS;
  const int tid = threadIdx.x;
  const int wave = tid >> 6, lane = tid & 63;
  const int quad = lane >> 4, l16 = lane & 15;

  float* out_ax = dout + OUT_OFF;     // ax aliased into 'out' region
  float* hlin   = dout + HLIN_OFF;    // ad aliased here (consumed per step)
  float* logh   = dout + LOGH_OFF;
  float* signh  = dout + SIGNH_OFF;
  const float* scales = (const float*)(ws + WS_SCALES);
  unsigned* comm = (unsigned*)(ws + WS_COMM);   // dwords: [2][8][1024] = [buf][b][row]

  __shared__ _Float16 hf[16*HFS];
  __shared__ floatx4 scr_v[4][64];
  __shared__ floatx4 scr_d[4][64];

  // zero pad batch rows 8..15 of hf (never re-written)
  for (int idx = tid; idx < 8*HFS; idx += 256) hf[8*HFS + idx] = (_Float16)0.f;

  // static A-fragments: weights * spectral scale, f16. A[m=l16][k=quad*8+j].
  const float sh = scales[0], sd = scales[1];
  half8 afv[8], afd[8];
  {
    const float* rv = Rh_raw + (size_t)(i0 + l16)*DD;
    const float* rd = Rd_raw + (size_t)(i0 + l16)*DD;
    for (int ks = 0; ks < 8; ++ks) {
      const int kb = wave*256 + ks*32 + quad*8;
      half8 hv, hd;
      #pragma unroll
      for (int j = 0; j < 8; ++j) {
        hv[j] = (_Float16)(rv[kb + j] * sh);
        hd[j] = (_Float16)(rd[kb + j] * sd);
      }
      afv[ks] = hv; afd[ks] = hd;
    }
  }

  // epilogue identity: tid<128 -> (row em, batch eb)
  const int em = tid & 15;
  const int eb = tid >> 4;
  const bool ep = (tid < 128);
  const int ei = i0 + em;
  float hp = 0.f;
  if (ep) hp = signh0[eb*DD + ei] * expf(logh0[eb*DD + ei]);

  __syncthreads();

  for (int t = 0; t < TSTEPS; ++t) {
    // prefetch ax/ad (HBM latency hidden under the payload spin)
    float axv = 0.f, adv = 0.f;
    if (ep) {
      axv = out_ax[(size_t)(t*8 + eb)*DD + ei];
      adv = hlin[(size_t)(t*8 + eb)*DD + ei];   // ad aliased; overwritten below
    }
    float vsum = 0.f, dsum = 0.f;
    if (t > 0) {
      // phase 1: spin directly on tagged payload buffer[(t-1)&1].
      // Each thread owns 32 dwords (stride-256 -> coalesced). First sweep
      // loads all 32 in flight; retries are predicated on pending bits so a
      // sweep costs one load-latency regardless of how many are pending.
      unsigned* src = comm + ((t-1)&1)*8192;
      const unsigned tagw = (unsigned)t;        // producers wrote (t-1)+1 = t
      unsigned pend = 0xffffffffu;
      do {
        unsigned np = 0u;
        #pragma unroll
        for (int q = 0; q < 32; ++q) {
          if (pend & (1u << q)) {
            const int w = q*256 + tid;
            const unsigned v = aload_u(src + w);
            // value halves land 2-lanes-per-bank: 2-way conflict = free
            *(unsigned short*)&hf[(w >> 10)*HFS + (w & 1023)] = (unsigned short)(v & 0xffffu);
            np |= ((v >> 16) != tagw) ? (1u << q) : 0u;
          }
        }
        pend = np;
      } while (__any(pend != 0u));
      __syncthreads();
      // phase 2: MFMA over this wave's K-slice (both matrices share B-frag)
      floatx4 av = {0.f,0.f,0.f,0.f}, ad2 = {0.f,0.f,0.f,0.f};
      const int kw = wave*256;
      #pragma unroll
      for (int ks = 0; ks < 8; ++ks) {
        half8 bfrag = *(const half8*)&hf[l16*HFS + kw + ks*32 + quad*8];
        av  = __builtin_amdgcn_mfma_f32_16x16x32_f16(afv[ks], bfrag, av,  0, 0, 0);
        ad2 = __builtin_amdgcn_mfma_f32_16x16x32_f16(afd[ks], bfrag, ad2, 0, 0, 0);
      }
      scr_v[wave][lane] = av;
      scr_d[wave][lane] = ad2;
      __syncthreads();
      if (ep) {
        // C[m][n]: lane=(m>>2)*16+n, reg=m&3
        const int rl = ((em >> 2) << 4) + eb;
        const int rr = em & 3;
        #pragma unroll
        for (int w2 = 0; w2 < 4; ++w2) {
          vsum += scr_v[w2][rl][rr];
          dsum += scr_d[w2][rl][rr];
        }
      }
    }
    // phase 3: epilogue; publish tagged payload dword (fire-and-forget, no
    // vmcnt, no flag), then off-critical-path output stores.
    if (ep) {
      float v  = axv + vsum;
      float dd = adv + dsum;
      float cand  = tanhf(v);
      float delta = 1.f/(1.f + expf(-dd));
      float hn = (1.f - delta)*hp + delta*cand;
      hp = hn;
      float logv = logf(fabsf(hn) + 1e-12f);
      float sgn = (hn >= 0.f) ? 1.f : -1.f;
      unsigned pd = ((unsigned)(t + 1) << 16) |
                    (unsigned)__half_as_ushort(__float2half(hn));
      astore_u(comm + (t & 1)*8192 + eb*1024 + ei, pd);
      const size_t oidx = (size_t)(t*8 + eb)*DD + ei;
      hlin[oidx] = hn;
      logh[(size_t)((t+1)*8 + eb)*DD + ei] = logv;
      signh[(size_t)((t+1)*8 + eb)*DD + ei] = sgn;
    }
  }
}

// ============================================================================
// out = softmax(h over groups of 32) * silu(h @ W_out^T), element-wise rewrite.
// ============================================================================
__global__ __launch_bounds__(256) void out_epilogue(
    const float* __restrict__ hlin, float* __restrict__ y_out) {
  const int row = blockIdx.x;          // t*8+b
  const int tid = threadIdx.x;
  const float* h = hlin + (size_t)row*DD;
  float* yo = y_out + (size_t)row*DD;
  const int e = tid*4;
  float4 hv = *(const float4*)(h + e);
  float4 yv = *(const float4*)(yo + e);
  float m = fmaxf(fmaxf(hv.x,hv.y), fmaxf(hv.z,hv.w));
  #pragma unroll
  for (int off = 1; off < 8; off <<= 1) m = fmaxf(m, __shfl_xor(m, off));
  float e0 = expf(hv.x - m), e1 = expf(hv.y - m), e2 = expf(hv.z - m), e3 = expf(hv.w - m);
  float s = e0+e1+e2+e3;
  #pragma unroll
  for (int off = 1; off < 8; off <<= 1) s += __shfl_xor(s, off);
  float inv = 1.f/s;
  float4 o;
  o.x = e0*inv * (yv.x/(1.f+expf(-yv.x)));
  o.y = e1*inv * (yv.y/(1.f+expf(-yv.y)));
  o.z = e2*inv * (yv.z/(1.f+expf(-yv.z)));
  o.w = e3*inv * (yv.w/(1.f+expf(-yv.w)));
  *(float4*)(yo + e) = o;
}

__global__ __launch_bounds__(256) void init_rows(
    const float* __restrict__ lh0, const float* __restrict__ sh0, float* __restrict__ dout) {
  int idx = blockIdx.x*256 + threadIdx.x;   // 8192
  dout[LOGH_OFF + idx]  = lh0[idx];
  dout[SIGNH_OFF + idx] = sh0[idx];
}

extern "C" void kernel_launch(void* const* d_in, const int* in_sizes, int n_in,
                              void* d_out, int out_size, void* d_ws, size_t ws_size,
                              hipStream_t stream) {
  const float* x      = (const float*)d_in[0];
  const float* logh0  = (const float*)d_in[1];
  const float* signh0 = (const float*)d_in[2];
  const float* Rh_raw = (const float*)d_in[3];
  const float* Rx     = (const float*)d_in[4];
  const float* Rd_raw = (const float*)d_in[5];
  const float* Wdelta = (const float*)d_in[6];
  const float* Wout   = (const float*)d_in[7];
  const float* bvec   = (const float*)d_in[8];
  const float* bdelta = (const float*)d_in[9];
  const float* uh     = (const float*)d_in[10];
  const float* ud     = (const float*)d_in[11];
  float* out = (float*)d_out;
  unsigned char* ws = (unsigned char*)d_ws;

  // zero scales/sumsq/cnts AND the tagged comm region (stale tags from a
  // previous replay would alias with this run's step tags)
  hipMemsetAsync(ws, 0, WS_COMM + 2*8192*4, stream);
  spectral_kernel<<<128, 256, 0, stream>>>(Rh_raw, Rd_raw, uh, ud, ws);
  // ax -> out region, ad -> h_lin region (dead-aliased scratch)
  gemm_f16<<<dim3(16,128), 256, 0, stream>>>(x, Rx, Wdelta, bvec, bdelta,
                                             out + OUT_OFF, out + HLIN_OFF);
  init_rows<<<32, 256, 0, stream>>>(logh0, signh0, out);
  recurrence_kernel<<<NWG, 256, 0, stream>>>(Rh_raw, Rd_raw, logh0, signh0, out, ws);
  // Y = h_lin @ W_out^T -> out region (ax dead)
  gemm_f16<<<dim3(16,128), 256, 0, stream>>>(out + HLIN_OFF, Wout, nullptr, nullptr, nullptr,
                                             out + OUT_OFF, nullptr);
  out_epilogue<<<8192, 256, 0, stream>>>(out + HLIN_OFF, out + OUT_OFF);
}

// Round 2
// 4460.991 us; speedup vs baseline: 2.3938x; 2.3938x over previous
//
#include <hip/hip_runtime.h>
#include <hip/hip_fp16.h>

#define DD 1024
#define TSTEPS 1024
#define BATCH 8
#define NWG 64
#define ROWS 16
#define HFS 1028   // LDS hf row stride in halves (514 dwords, 514%32=2 -> conflict-free-ish)

typedef _Float16 half8 __attribute__((ext_vector_type(8)));
typedef float floatx4 __attribute__((ext_vector_type(4)));

// ---- d_out float offsets ----
#define OUT_OFF   0
#define LOGH_OFF  8388608
#define SIGNH_OFF 16785408
#define HLIN_OFF  25182208

// ---- ws byte offsets ----
#define WS_SCALES  0          // float[2]
#define WS_SUMSQ   64         // float[2][8]
#define WS_FLAGS   128        // int[64]  recurrence per-WG monotonic flags -> [128,384)
#define WS_CNTS    384        // int[2][8] spectral barriers -> [384,448)
#define WS_SPECVEC 512        // float[2][2][1024] power-iter ping-pong -> [512,16896)
#define WS_COMM    16896      // ushort[2][8][1024] packed f16 h double-buffer -> [16896,49664)

__device__ __forceinline__ int aload_i(int* p) { return __hip_atomic_load(p, __ATOMIC_RELAXED, __HIP_MEMORY_SCOPE_AGENT); }
__device__ __forceinline__ float aload_f(float* p) { return __hip_atomic_load(p, __ATOMIC_RELAXED, __HIP_MEMORY_SCOPE_AGENT); }
__device__ __forceinline__ unsigned aload_u(unsigned* p) { return __hip_atomic_load(p, __ATOMIC_RELAXED, __HIP_MEMORY_SCOPE_AGENT); }
__device__ __forceinline__ void astore_f(float* p, float v) { __hip_atomic_store(p, v, __ATOMIC_RELAXED, __HIP_MEMORY_SCOPE_AGENT); }
__device__ __forceinline__ void astore_i(int* p, int v) { __hip_atomic_store(p, v, __ATOMIC_RELAXED, __HIP_MEMORY_SCOPE_AGENT); }
__device__ __forceinline__ void astore_u(unsigned* p, unsigned v) { __hip_atomic_store(p, v, __ATOMIC_RELAXED, __HIP_MEMORY_SCOPE_AGENT); }
__device__ __forceinline__ void aadd_i(int* p, int v) { (void)__hip_atomic_fetch_add(p, v, __ATOMIC_RELAXED, __HIP_MEMORY_SCOPE_AGENT); }
__device__ __forceinline__ void waitcnt_vm0() { asm volatile("s_waitcnt vmcnt(0)" ::: "memory"); }

// ============================================================================
// Spectral norm: 3-step power iteration for both matrices concurrently.
// ============================================================================
__global__ __launch_bounds__(256) void spectral_kernel(
    const float* __restrict__ Wh, const float* __restrict__ Wd,
    const float* __restrict__ uh, const float* __restrict__ ud,
    unsigned char* __restrict__ ws) {
  const int g  = blockIdx.x >> 6;
  const int wg = blockIdx.x & 63;
  const int tid = threadIdx.x;
  const float* W  = g ? Wd : Wh;
  const float* u0 = g ? ud : uh;
  float* scales = (float*)(ws + WS_SCALES);
  float* sumsq  = (float*)(ws + WS_SUMSQ) + g*8;
  int*   cnt    = (int*)(ws + WS_CNTS) + g*8;
  float* ubuf   = (float*)(ws + WS_SPECVEC) + g*2048;
  float* vbuf   = ubuf + 1024;

  __shared__ float xs[1024];
  __shared__ float tileW[256*17];
  __shared__ float red[16*17];

  float ss = 0.f;
  for (int i2 = tid; i2 < 1024; i2 += 256) { float x = u0[i2]; ss += x*x; }
  #pragma unroll
  for (int off = 1; off < 64; off <<= 1) ss += __shfl_xor(ss, off);
  if ((tid & 63) == 0) red[tid >> 6] = ss;
  __syncthreads();
  float inv_prev = 1.f/(sqrtf(red[0]+red[1]+red[2]+red[3]) + 1e-8f);
  __syncthreads();

  for (int p = 1; p <= 6; ++p) {
    const int colmv = p & 1;
    float* dst  = colmv ? vbuf : ubuf;
    float* srcw = colmv ? ubuf : vbuf;
    float part = 0.f;
    if (colmv) {
      const int jb = wg*16;
      const int jl = tid & 15, is = tid >> 4;
      float acc = 0.f;
      for (int i0 = 0; i0 < 1024; i0 += 256) {
        __syncthreads();
        float xv = (p == 1) ? u0[i0 + tid] : aload_f(srcw + i0 + tid);
        xs[tid] = xv * inv_prev;
        const float* wr = W + (size_t)(i0 + tid)*DD + jb;
        float4 a = *(const float4*)(wr + 0);
        float4 bq = *(const float4*)(wr + 4);
        float4 cq = *(const float4*)(wr + 8);
        float4 dq = *(const float4*)(wr + 12);
        float* tr = tileW + tid*17;
        tr[0]=a.x; tr[1]=a.y; tr[2]=a.z; tr[3]=a.w;
        tr[4]=bq.x; tr[5]=bq.y; tr[6]=bq.z; tr[7]=bq.w;
        tr[8]=cq.x; tr[9]=cq.y; tr[10]=cq.z; tr[11]=cq.w;
        tr[12]=dq.x; tr[13]=dq.y; tr[14]=dq.z; tr[15]=dq.w;
        __syncthreads();
        #pragma unroll 4
        for (int ii = 0; ii < 16; ++ii)
          acc += tileW[(is*16 + ii)*17 + jl] * xs[is*16 + ii];
      }
      __syncthreads();
      red[is*17 + jl] = acc;
      __syncthreads();
      if (tid < 16) {
        float y = 0.f;
        #pragma unroll
        for (int k = 0; k < 16; ++k) y += red[k*17 + tid];
        astore_f(dst + jb + tid, y);
        part = y*y;
      }
    } else {
      const int ib = wg*16;
      for (int i2 = tid; i2 < 1024; i2 += 256) xs[i2] = aload_f(srcw + i2) * inv_prev;
      __syncthreads();
      const int r = tid >> 4, s = tid & 15;
      const float* wr = W + (size_t)(ib + r)*DD;
      float acc = 0.f;
      #pragma unroll 8
      for (int jj = 0; jj < 64; ++jj) {
        int j = s + (jj << 4);
        acc += wr[j] * xs[j];
      }
      #pragma unroll
      for (int off = 1; off < 16; off <<= 1) acc += __shfl_xor(acc, off);
      __syncthreads();
      if (s == 0) red[r] = acc;
      __syncthreads();
      if (tid < 16) {
        float y = red[tid];
        astore_f(dst + ib + tid, y);
        part = y*y;
      }
    }
    #pragma unroll
    for (int off = 1; off < 16; off <<= 1) part += __shfl_xor(part, off);
    if (tid == 0) atomicAdd(sumsq + p, part);
    waitcnt_vm0();
    __syncthreads();
    if (tid == 0) {
      aadd_i(cnt + p, 1);
      while (aload_i(cnt + p) < 64) __builtin_amdgcn_s_sleep(1);
    }
    __syncthreads();
    float stot = aload_f(sumsq + p);
    inv_prev = 1.f/(sqrtf(stot) + 1e-8f);
    __syncthreads();
  }
  if (wg == 0 && tid == 0) {
    float n2 = aload_f(sumsq + 6);
    float nn = sqrtf(n2);
    float sigma = (nn*nn)/(nn + 1e-8f);
    scales[g] = 0.99f/(sigma + 1e-8f);
  }
}

// ============================================================================
// f16 MFMA GEMM (dual-B variant shares the A tile). M=8192, N=K=1024.
// ============================================================================
__device__ __forceinline__ half8 cvt8(const float* p) {
  float4 lo = *(const float4*)p;
  float4 hi = *(const float4*)(p+4);
  half8 h;
  h[0]=(_Float16)lo.x; h[1]=(_Float16)lo.y; h[2]=(_Float16)lo.z; h[3]=(_Float16)lo.w;
  h[4]=(_Float16)hi.x; h[5]=(_Float16)hi.y; h[6]=(_Float16)hi.z; h[7]=(_Float16)hi.w;
  return h;
}

__global__ __launch_bounds__(256) void gemm_f16(
    const float* __restrict__ A,
    const float* __restrict__ B1, const float* __restrict__ B2,
    const float* __restrict__ bias1, const float* __restrict__ bias2,
    float* __restrict__ C1, float* __restrict__ C2) {
  const int n0 = blockIdx.x * 64;
  const int m0 = blockIdx.y * 64;
  const int tid = threadIdx.x;
  const int wave = tid >> 6, lane = tid & 63;
  const int quad = lane >> 4, l16 = lane & 15;
  const bool dual = (B2 != nullptr);
  __shared__ _Float16 As[64*40];
  __shared__ _Float16 Bs1[64*40];
  __shared__ _Float16 Bs2[64*40];
  floatx4 zero = {0.f,0.f,0.f,0.f};
  floatx4 acc1[2][2] = {{zero,zero},{zero,zero}};
  floatx4 acc2[2][2] = {{zero,zero},{zero,zero}};
  const int srow = tid >> 2;
  const int sseg = (tid & 3) * 8;
  const int mb = (wave >> 1)*32, nb = (wave & 1)*32;
  for (int k0 = 0; k0 < 1024; k0 += 32) {
    __syncthreads();
    *(half8*)&As[srow*40 + sseg]  = cvt8(A  + (size_t)(m0+srow)*DD + k0 + sseg);
    *(half8*)&Bs1[srow*40 + sseg] = cvt8(B1 + (size_t)(n0+srow)*DD + k0 + sseg);
    if (dual) *(half8*)&Bs2[srow*40 + sseg] = cvt8(B2 + (size_t)(n0+srow)*DD + k0 + sseg);
    __syncthreads();
    half8 a0 = *(const half8*)&As[(mb + l16)*40 + quad*8];
    half8 a1 = *(const half8*)&As[(mb + 16 + l16)*40 + quad*8];
    half8 b0 = *(const half8*)&Bs1[(nb + l16)*40 + quad*8];
    half8 b1 = *(const half8*)&Bs1[(nb + 16 + l16)*40 + quad*8];
    acc1[0][0] = __builtin_amdgcn_mfma_f32_16x16x32_f16(a0, b0, acc1[0][0], 0,0,0);
    acc1[0][1] = __builtin_amdgcn_mfma_f32_16x16x32_f16(a0, b1, acc1[0][1], 0,0,0);
    acc1[1][0] = __builtin_amdgcn_mfma_f32_16x16x32_f16(a1, b0, acc1[1][0], 0,0,0);
    acc1[1][1] = __builtin_amdgcn_mfma_f32_16x16x32_f16(a1, b1, acc1[1][1], 0,0,0);
    if (dual) {
      half8 c0 = *(const half8*)&Bs2[(nb + l16)*40 + quad*8];
      half8 c1 = *(const half8*)&Bs2[(nb + 16 + l16)*40 + quad*8];
      acc2[0][0] = __builtin_amdgcn_mfma_f32_16x16x32_f16(a0, c0, acc2[0][0], 0,0,0);
      acc2[0][1] = __builtin_amdgcn_mfma_f32_16x16x32_f16(a0, c1, acc2[0][1], 0,0,0);
      acc2[1][0] = __builtin_amdgcn_mfma_f32_16x16x32_f16(a1, c0, acc2[1][0], 0,0,0);
      acc2[1][1] = __builtin_amdgcn_mfma_f32_16x16x32_f16(a1, c1, acc2[1][1], 0,0,0);
    }
  }
  #pragma unroll
  for (int in = 0; in < 2; ++in) {
    const int n = n0 + nb + in*16 + l16;
    const float bv1 = bias1 ? bias1[n] : 0.f;
    const float bv2 = (dual && bias2) ? bias2[n] : 0.f;
    #pragma unroll
    for (int im = 0; im < 2; ++im) {
      const int mrow = m0 + mb + im*16 + quad*4;
      floatx4 c = acc1[im][in];
      #pragma unroll
      for (int r2 = 0; r2 < 4; ++r2) C1[(size_t)(mrow + r2)*DD + n] = c[r2] + bv1;
      if (dual) {
        floatx4 c2 = acc2[im][in];
        #pragma unroll
        for (int r2 = 0; r2 < 4; ++r2) C2[(size_t)(mrow + r2)*DD + n] = c2[r2] + bv2;
      }
    }
  }
}

// ============================================================================
// Persistent recurrence, flag-synced (round-0 protocol) with two latency
// fixes:
//  (a) bulk payload read is register-staged: all 16 agent loads issue
//      back-to-back into VGPRs (one LLC latency, pipelined) and only then
//      land in LDS — the load/ds_write interleave serialized ~16 LLC
//      round-trips per step before;
//  (b) all 4 waves poll the flag array directly (no wave0-detect +
//      broadcast barrier). Safe: a wave passing the poll for step t implies
//      its own WG published t-1, which implies all waves passed the pack
//      barrier and are done reading hf — the flag doubles as the hf guard.
// Producer side unchanged: payload store -> vmcnt(0) -> flags[wg]=t+1.
// ============================================================================
__global__ __launch_bounds__(256, 1) void recurrence_kernel(
    const float* __restrict__ Rh_raw, const float* __restrict__ Rd_raw,
    const float* __restrict__ logh0, const float* __restrict__ signh0,
    float* __restrict__ dout, unsigned char* __restrict__ ws) {
  const int wg = blockIdx.x;
  const int i0 = wg * ROWS;
  const int tid = threadIdx.x;
  const int wave = tid >> 6, lane = tid & 63;
  const int quad = lane >> 4, l16 = lane & 15;

  float* out_ax = dout + OUT_OFF;     // ax aliased into 'out' region
  float* hlin   = dout + HLIN_OFF;    // ad aliased here (consumed per step)
  float* logh   = dout + LOGH_OFF;
  float* signh  = dout + SIGNH_OFF;
  const float* scales = (const float*)(ws + WS_SCALES);
  unsigned* comm = (unsigned*)(ws + WS_COMM);   // dwords: [2][8][512]
  int* flags = (int*)(ws + WS_FLAGS);           // int[64], monotonic

  __shared__ _Float16 hf[16*HFS];
  __shared__ floatx4 scr_v[4][64];
  __shared__ floatx4 scr_d[4][64];
  __shared__ unsigned hs[64];                   // this WG's packed payload

  // zero pad batch rows 8..15 of hf (never re-written)
  for (int idx = tid; idx < 8*HFS; idx += 256) hf[8*HFS + idx] = (_Float16)0.f;

  // static A-fragments: weights * spectral scale, f16. A[m=l16][k=quad*8+j].
  const float sh = scales[0], sd = scales[1];
  half8 afv[8], afd[8];
  {
    const float* rv = Rh_raw + (size_t)(i0 + l16)*DD;
    const float* rd = Rd_raw + (size_t)(i0 + l16)*DD;
    for (int ks = 0; ks < 8; ++ks) {
      const int kb = wave*256 + ks*32 + quad*8;
      half8 hv, hd;
      #pragma unroll
      for (int j = 0; j < 8; ++j) {
        hv[j] = (_Float16)(rv[kb + j] * sh);
        hd[j] = (_Float16)(rd[kb + j] * sd);
      }
      afv[ks] = hv; afd[ks] = hd;
    }
  }

  // epilogue identity: tid<128 -> (row em, batch eb)
  const int em = tid & 15;
  const int eb = tid >> 4;
  const bool ep = (tid < 128);
  const int ei = i0 + em;
  float hp = 0.f;
  if (ep) hp = signh0[eb*DD + ei] * expf(logh0[eb*DD + ei]);

  __syncthreads();

  for (int t = 0; t < TSTEPS; ++t) {
    // prefetch ax/ad (HBM latency hidden under the poll)
    float axv = 0.f, adv = 0.f;
    if (ep) {
      axv = out_ax[(size_t)(t*8 + eb)*DD + ei];
      adv = hlin[(size_t)(t*8 + eb)*DD + ei];   // ad aliased; overwritten below
    }
    float vsum = 0.f, dsum = 0.f;
    if (t > 0) {
      // phase 1: every wave polls the 64-int flag array (one coalesced load
      // per round). Passing implies own WG published t-1 -> hf reads done.
      {
        unsigned long long mask;
        do {
          int fv = aload_i(flags + lane);
          mask = __ballot(fv >= t);
        } while (mask != ~0ull);
      }
      // phase 2: bulk-read payload buffer[(t-1)&1] -> registers (16 loads
      // in flight, ~1 LLC latency), then -> LDS.
      {
        unsigned* src = comm + ((t-1)&1)*4096;
        unsigned rbuf[16];
        #pragma unroll
        for (int q = 0; q < 16; ++q) rbuf[q] = aload_u(src + q*256 + tid);
        #pragma unroll
        for (int q = 0; q < 16; ++q) {
          const int w = q*256 + tid;
          const int b2 = w >> 9;           // 512 dwords per batch row
          const int k2 = w & 511;
          *(unsigned*)&hf[b2*HFS + k2*2] = rbuf[q];
        }
      }
      __syncthreads();
      // phase 3: MFMA over this wave's K-slice (both matrices share B-frag)
      floatx4 av = {0.f,0.f,0.f,0.f}, ad2 = {0.f,0.f,0.f,0.f};
      const int kw = wave*256;
      #pragma unroll
      for (int ks = 0; ks < 8; ++ks) {
        half8 bfrag = *(const half8*)&hf[l16*HFS + kw + ks*32 + quad*8];
        av  = __builtin_amdgcn_mfma_f32_16x16x32_f16(afv[ks], bfrag, av,  0, 0, 0);
        ad2 = __builtin_amdgcn_mfma_f32_16x16x32_f16(afd[ks], bfrag, ad2, 0, 0, 0);
      }
      scr_v[wave][lane] = av;
      scr_d[wave][lane] = ad2;
      __syncthreads();
      if (ep) {
        // C[m][n]: lane=(m>>2)*16+n, reg=m&3
        const int rl = ((em >> 2) << 4) + eb;
        const int rr = em & 3;
        #pragma unroll
        for (int w2 = 0; w2 < 4; ++w2) {
          vsum += scr_v[w2][rl][rr];
          dsum += scr_d[w2][rl][rr];
        }
      }
    }
    // phase 4: epilogue; hn f16 -> LDS hs (outputs held back)
    float hn = 0.f, logv = 0.f, sgn = 1.f;
    if (ep) {
      float v  = axv + vsum;
      float dd = adv + dsum;
      float cand  = tanhf(v);
      float delta = 1.f/(1.f + expf(-dd));
      hn = (1.f - delta)*hp + delta*cand;
      hp = hn;
      logv = logf(fabsf(hn) + 1e-12f);
      sgn = (hn >= 0.f) ? 1.f : -1.f;
      ((unsigned short*)hs)[eb*16 + em] = __half_as_ushort(__float2half(hn));
    }
    __syncthreads();
    // phase 5: wave0 publishes payload + release flag (critical path)
    if (wave == 0) {
      const int eb2 = lane >> 3, pr = lane & 7;
      unsigned d = hs[eb2*8 + pr];
      astore_u(comm + (t&1)*4096 + eb2*512 + wg*8 + pr, d);
      waitcnt_vm0();
      if (lane == 0) astore_i(flags + wg, t + 1);
    }
    // phase 6: off-critical-path output stores
    if (ep) {
      const size_t oidx = (size_t)(t*8 + eb)*DD + ei;
      hlin[oidx] = hn;
      logh[(size_t)((t+1)*8 + eb)*DD + ei] = logv;
      signh[(size_t)((t+1)*8 + eb)*DD + ei] = sgn;
    }
  }
}

// ============================================================================
// out = softmax(h over groups of 32) * silu(h @ W_out^T), element-wise rewrite.
// ============================================================================
__global__ __launch_bounds__(256) void out_epilogue(
    const float* __restrict__ hlin, float* __restrict__ y_out) {
  const int row = blockIdx.x;          // t*8+b
  const int tid = threadIdx.x;
  const float* h = hlin + (size_t)row*DD;
  float* yo = y_out + (size_t)row*DD;
  const int e = tid*4;
  float4 hv = *(const float4*)(h + e);
  float4 yv = *(const float4*)(yo + e);
  float m = fmaxf(fmaxf(hv.x,hv.y), fmaxf(hv.z,hv.w));
  #pragma unroll
  for (int off = 1; off < 8; off <<= 1) m = fmaxf(m, __shfl_xor(m, off));
  float e0 = expf(hv.x - m), e1 = expf(hv.y - m), e2 = expf(hv.z - m), e3 = expf(hv.w - m);
  float s = e0+e1+e2+e3;
  #pragma unroll
  for (int off = 1; off < 8; off <<= 1) s += __shfl_xor(s, off);
  float inv = 1.f/s;
  float4 o;
  o.x = e0*inv * (yv.x/(1.f+expf(-yv.x)));
  o.y = e1*inv * (yv.y/(1.f+expf(-yv.y)));
  o.z = e2*inv * (yv.z/(1.f+expf(-yv.z)));
  o.w = e3*inv * (yv.w/(1.f+expf(-yv.w)));
  *(float4*)(yo + e) = o;
}

__global__ __launch_bounds__(256) void init_rows(
    const float* __restrict__ lh0, const float* __restrict__ sh0, float* __restrict__ dout) {
  int idx = blockIdx.x*256 + threadIdx.x;   // 8192
  dout[LOGH_OFF + idx]  = lh0[idx];
  dout[SIGNH_OFF + idx] = sh0[idx];
}

extern "C" void kernel_launch(void* const* d_in, const int* in_sizes, int n_in,
                              void* d_out, int out_size, void* d_ws, size_t ws_size,
                              hipStream_t stream) {
  const float* x      = (const float*)d_in[0];
  const float* logh0  = (const float*)d_in[1];
  const float* signh0 = (const float*)d_in[2];
  const float* Rh_raw = (const float*)d_in[3];
  const float* Rx     = (const float*)d_in[4];
  const float* Rd_raw = (const float*)d_in[5];
  const float* Wdelta = (const float*)d_in[6];
  const float* Wout   = (const float*)d_in[7];
  const float* bvec   = (const float*)d_in[8];
  const float* bdelta = (const float*)d_in[9];
  const float* uh     = (const float*)d_in[10];
  const float* ud     = (const float*)d_in[11];
  float* out = (float*)d_out;
  unsigned char* ws = (unsigned char*)d_ws;

  hipMemsetAsync(ws, 0, 512, stream);   // scales/sumsq/flags/cnts
  spectral_kernel<<<128, 256, 0, stream>>>(Rh_raw, Rd_raw, uh, ud, ws);
  // ax -> out region, ad -> h_lin region (dead-aliased scratch)
  gemm_f16<<<dim3(16,128), 256, 0, stream>>>(x, Rx, Wdelta, bvec, bdelta,
                                             out + OUT_OFF, out + HLIN_OFF);
  init_rows<<<32, 256, 0, stream>>>(logh0, signh0, out);
  recurrence_kernel<<<NWG, 256, 0, stream>>>(Rh_raw, Rd_raw, logh0, signh0, out, ws);
  // Y = h_lin @ W_out^T -> out region (ax dead)
  gemm_f16<<<dim3(16,128), 256, 0, stream>>>(out + HLIN_OFF, Wout, nullptr, nullptr, nullptr,
                                             out + OUT_OFF, nullptr);
  out_epilogue<<<8192, 256, 0, stream>>>(out + HLIN_OFF, out + OUT_OFF);
}